// Round 8
// baseline (242.800 us; speedup 1.0000x reference)
//
#include <hip/hip_runtime.h>

// FWHT over last dim (4096) of [8192, 4096] fp32, normalized by 1/64.
// Round-8: SOFTWARE-PIPELINED PERSISTENT WAVES. Same bit-exact shuffle math
// as R5/R7 (zero LDS, zero barriers), but each wave now processes 4
// consecutive rows through TWO register row-buffers so vmem ops are in
// flight during 100% of the wave's life (the property shared by the only
// 6+ TB/s kernels measured on this chip: copy/fill grid-stride loops).
//
// Per-wave schedule (fully unrolled, static register buffers va/vb):
//   load A(r0) ; load B(r0+1)
//   compute A ; store A ; load A(r0+2)     <- B's 16 loads still in flight
//   compute B ; store B ; load B(r0+3)     <- A's loads + A's stores in flight
//   compute A ; store A
//   compute B ; store B
// Compiler dependency tracking emits counted vmcnt (16/32), never a drain:
// when compute X starts, buffer Y's 16 loads (and older stores) remain
// outstanding. Steady-state in-flight per wave = 32-48 KB; 8 waves/CU ->
// ~10x the ~25 KB/CU Little's-law requirement for 6.3 TB/s.
//
// Math layout (identical to R5, absmax 0.0 verified): element
// e = i*256 + 4l + j -> e[1:0]=j in-reg, e[7:2]=lane, e[11:8]=i. Stages
// strictly LSB->MSB = reference summation tree:
//   bits 0..1 in-register; bits 2..7 cross-lane __shfl_xor masks 1..32
//   (butterfly fmaf(+/-1, own, partner) is exact); bits 8..11 in-register.

#define N        4096
#define THREADS  256          // 4 waves per block, independent
#define RPW      4            // rows per wave

__device__ __forceinline__ void fwht_row(float v[64], const int l) {
    // bits 0..1: in-register (within each float4 chunk)
#pragma unroll
    for (int s = 1; s < 4; s <<= 1) {
#pragma unroll
        for (int k = 0; k < 64; k++) {
            if ((k & s) == 0) {
                float a = v[k], b = v[k + s];
                v[k] = a + b;
                v[k + s] = a - b;
            }
        }
    }
    // bits 2..7: cross-lane butterflies, masks 1..32 (LSB->MSB)
#pragma unroll
    for (int m = 1; m < 64; m <<= 1) {
        const float sgn = (l & m) ? -1.0f : 1.0f;
#pragma unroll
        for (int r = 0; r < 64; r++) {
            float p = __shfl_xor(v[r], m, 64);
            v[r] = fmaf(sgn, v[r], p);   // lo: own+p = a+b ; hi: p-own = a-b
        }
    }
    // bits 8..11: in-register (across the 16 chunks)
#pragma unroll
    for (int s = 4; s < 64; s <<= 1) {
#pragma unroll
        for (int k = 0; k < 64; k++) {
            if ((k & s) == 0) {
                float a = v[k], b = v[k + s];
                v[k] = a + b;
                v[k + s] = a - b;
            }
        }
    }
}

__global__ __launch_bounds__(THREADS)
void FWHT_83476984365427_kernel(const float* __restrict__ x,
                                float* __restrict__ out,
                                int nrows) {
    const int wid = blockIdx.x * (THREADS / 64) + (threadIdx.x >> 6);
    const int l   = threadIdx.x & 63;
    const int r0  = wid * RPW;
    if (r0 >= nrows) return;

    float va[64], vb[64];
    const float scale = 1.0f / 64.0f;

    // 16 x dwordx4, each 1 KB wave-contiguous.
#define LOADROW(v_, row_)                                                  \
    {                                                                      \
        const float* __restrict__ xr_ = x + (size_t)(row_) * N;            \
        _Pragma("unroll")                                                  \
        for (int i = 0; i < 16; i++) {                                     \
            float4 f = *(const float4*)(xr_ + i * 256 + l * 4);            \
            v_[4 * i + 0] = f.x; v_[4 * i + 1] = f.y;                      \
            v_[4 * i + 2] = f.z; v_[4 * i + 3] = f.w;                      \
        }                                                                  \
    }

#define STOREROW(v_, row_)                                                 \
    {                                                                      \
        float* __restrict__ or_ = out + (size_t)(row_) * N;                \
        _Pragma("unroll")                                                  \
        for (int i = 0; i < 16; i++) {                                     \
            float4 f;                                                      \
            f.x = v_[4 * i + 0] * scale; f.y = v_[4 * i + 1] * scale;      \
            f.z = v_[4 * i + 2] * scale; f.w = v_[4 * i + 3] * scale;      \
            *(float4*)(or_ + i * 256 + l * 4) = f;                         \
        }                                                                  \
    }

    if (r0 + RPW <= nrows) {
        // Steady-state pipeline, fully unrolled, RPW = 4.
        LOADROW(va, r0 + 0);
        LOADROW(vb, r0 + 1);

        fwht_row(va, l);                 // waits vmcnt(16): vb still in flight
        STOREROW(va, r0 + 0);
        LOADROW(va, r0 + 2);             // refill A behind B

        fwht_row(vb, l);                 // vmcnt(32): A-stores + A'-loads fly
        STOREROW(vb, r0 + 1);
        LOADROW(vb, r0 + 3);

        fwht_row(va, l);
        STOREROW(va, r0 + 2);

        fwht_row(vb, l);
        STOREROW(vb, r0 + 3);
    } else {
        // Tail (not hit at 8192 rows, kept for generality).
        for (int r = r0; r < nrows; r++) {
            LOADROW(va, r);
            fwht_row(va, l);
            STOREROW(va, r);
        }
    }
#undef LOADROW
#undef STOREROW
}

extern "C" void kernel_launch(void* const* d_in, const int* in_sizes, int n_in,
                              void* d_out, int out_size, void* d_ws, size_t ws_size,
                              hipStream_t stream) {
    (void)n_in; (void)d_ws; (void)ws_size; (void)out_size;
    const float* x = (const float*)d_in[0];
    float* out = (float*)d_out;
    const int nrows = in_sizes[0] / N;
    const int waves = (nrows + RPW - 1) / RPW;
    const int wpb   = THREADS / 64;
    dim3 grid((waves + wpb - 1) / wpb);
    dim3 block(THREADS);
    FWHT_83476984365427_kernel<<<grid, block, 0, stream>>>(x, out, nrows);
}